// Round 1
// baseline (3769.986 us; speedup 1.0000x reference)
//
#include <hip/hip_runtime.h>
#include <hip/hip_fp16.h>

// LSTM Autoencoder: B=256, T=128, I=512, H=1024, E=256
// Strategy: per-timestep fused MFMA-fp16 GEMM + gate epilogue kernels.
//  - fp16 inputs to MFMA, fp32 accumulate, fp32 cell state (accuracy).
//  - encoder: K = 1536 (x_t folded in; same total FLOPs as precomputing x_proj).
//  - decoder: W_rec = dec_Wih[:,H:] + dec_Whh precombined; "fixed" term is a
//    per-(b,gatecol) bias matrix.
//  - grid (colblock, rowblock) with colblock fastest => same-col row-blocks
//    share an XCD => weight slices are L2-resident across the 8-way batch reuse.

#define B_ 256
#define T_ 128
#define I_ 512
#define H_ 1024
#define E_ 256

typedef _Float16 half8 __attribute__((ext_vector_type(8)));
typedef float floatx4 __attribute__((ext_vector_type(4)));

__device__ __forceinline__ float sigmoidf_(float x) {
    return 1.0f / (1.0f + __expf(-x));
}
__device__ __forceinline__ float tanhf_(float x) {
    x = fminf(fmaxf(x, -15.0f), 15.0f);
    float e = __expf(2.0f * x);
    return (e - 1.0f) / (e + 1.0f);
}

// ---------------- setup kernels ----------------

__global__ void cast_x_kernel(const float* __restrict__ x, _Float16* __restrict__ x16, int n8) {
    int i = blockIdx.x * blockDim.x + threadIdx.x;   // one thread per 8 elems
    if (i >= n8) return;
    const float4* p = (const float4*)x + (size_t)i * 2;
    float4 a = p[0], b = p[1];
    half8 h = { (_Float16)a.x, (_Float16)a.y, (_Float16)a.z, (_Float16)a.w,
                (_Float16)b.x, (_Float16)b.y, (_Float16)b.z, (_Float16)b.w };
    ((half8*)x16)[i] = h;
}

// Wc16[j][k] (j=gate-col 0..4095, k=0..1535): [Wih | Whh] row-major
__global__ void prep_encW_kernel(const float* __restrict__ Wih, const float* __restrict__ Whh,
                                 _Float16* __restrict__ Wc) {
    int k = blockIdx.x * 256 + threadIdx.x;   // 0..1535
    int j = blockIdx.y;                       // 0..4095
    float v = (k < I_) ? Wih[(size_t)j * I_ + k] : Whh[(size_t)j * H_ + (k - I_)];
    Wc[(size_t)j * 1536 + k] = (_Float16)v;
}

// Wr16[j][k] (j=0..2047, k=0..511): dec_Wih[:, H:] + dec_Whh
__global__ void prep_decW_kernel(const float* __restrict__ dWih, const float* __restrict__ dWhh,
                                 _Float16* __restrict__ Wr) {
    int k = blockIdx.x * 256 + threadIdx.x;   // 0..511
    int j = blockIdx.y;                       // 0..2047
    float v = dWih[(size_t)j * (H_ + I_) + H_ + k] + dWhh[(size_t)j * I_ + k];
    Wr[(size_t)j * I_ + k] = (_Float16)v;
}

__global__ void prep_bias_kernel(const float* __restrict__ a, const float* __restrict__ b,
                                 float* __restrict__ out) {
    int i = blockIdx.x * 256 + threadIdx.x;
    if (i < 4 * H_) out[i] = a[i] + b[i];
}

// ---------------- small fp32 GEMM: out[m,n] = act(sum_k A[m,k]*W[n,k] + b1[n] (+b2[n])) ----------------
__global__ __launch_bounds__(256) void small_gemm_kernel(
    const float* __restrict__ A, int lda,
    const float* __restrict__ W, int ldw,
    const float* __restrict__ b1, const float* __restrict__ b2,
    float* __restrict__ out, int N, int K, int relu)
{
    __shared__ float sA2[32][33];
    __shared__ float sW2[32][33];
    int tid = threadIdx.x;
    int tx = tid & 15, ty = tid >> 4;
    int m0 = blockIdx.y * 32, n0 = blockIdx.x * 32;
    float acc[2][2] = {};
    for (int k0 = 0; k0 < K; k0 += 32) {
        __syncthreads();
#pragma unroll
        for (int i = 0; i < 4; ++i) {
            int e = tid + i * 256;
            int r = e >> 5, c = e & 31;
            sA2[r][c] = A[(size_t)(m0 + r) * lda + k0 + c];
            sW2[r][c] = W[(size_t)(n0 + r) * ldw + k0 + c];
        }
        __syncthreads();
#pragma unroll
        for (int k = 0; k < 32; ++k) {
            float a0 = sA2[ty * 2][k], a1 = sA2[ty * 2 + 1][k];
            float w0 = sW2[tx * 2][k], w1 = sW2[tx * 2 + 1][k];
            acc[0][0] += a0 * w0; acc[0][1] += a0 * w1;
            acc[1][0] += a1 * w0; acc[1][1] += a1 * w1;
        }
    }
#pragma unroll
    for (int i = 0; i < 2; ++i)
#pragma unroll
        for (int j = 0; j < 2; ++j) {
            int m = m0 + ty * 2 + i, n = n0 + tx * 2 + j;
            float v = acc[i][j] + b1[n] + (b2 ? b2[n] : 0.0f);
            if (relu) v = fmaxf(v, 0.0f);
            out[(size_t)m * N + n] = v;
        }
}

// ---------------- fused LSTM step ----------------
// pre[b, n] = bias + sum_k A[b,k] * W[n,k];  n = gate*NH + hcol
// gates i,f,g,o; c = sig(f)*c + sig(i)*tanh(g); h = sig(o)*tanh(c)
// Block tile: 32 batch rows x 32 h-cols (=> 128 gate-cols). 256 threads / 4 waves.
// Wave w computes gate w's 32 cols (2 n-tiles of 16) x 2 m-tiles, mfma 16x16x32 f16.
template<int NH, int KD, bool HAS_X, bool BIAS_VEC, bool WRITE_OUT>
__global__ __launch_bounds__(256) void lstm_step_kernel(
    const _Float16* __restrict__ Ax, int t,
    const _Float16* __restrict__ Ah,
    const _Float16* __restrict__ W,
    const float* __restrict__ bias,      // BIAS_VEC ? [4*NH] : [B][4*NH]
    float* __restrict__ c_state,         // [B][NH], in-place
    _Float16* __restrict__ h_out,        // [B][NH]
    float* __restrict__ out32, int out_t)
{
    // LDS: A tile 32x64 halves (stride 72 => 144B rows, bank-rotating),
    //      B tile 128x64 halves (stride 72). Reused as fp32 pre[32][132] in epilogue.
    __shared__ alignas(16) char smem[32 * 72 * 2 + 128 * 72 * 2];
    _Float16 (*sA)[72] = (_Float16(*)[72])smem;
    _Float16 (*sB)[72] = (_Float16(*)[72])(smem + 32 * 72 * 2);

    const int tid = threadIdx.x;
    const int wave = tid >> 6, lane = tid & 63;
    const int q = lane >> 4, n15 = lane & 15;
    const int h0 = blockIdx.x * 32;    // h-col base
    const int row0 = blockIdx.y * 32;  // batch-row base

    floatx4 acc[2][2] = {};

    const int ar = tid >> 3, ac = tid & 7;   // staging: row 0..31, 16B-chunk 0..7

    for (int k0 = 0; k0 < KD; k0 += 64) {
        __syncthreads();
        // stage A tile: rows row0..row0+31, k in [k0, k0+64)
        {
            int k = k0 + ac * 8;
            const _Float16* src;
            if (HAS_X && k < I_) src = Ax + ((size_t)(row0 + ar) * T_ + t) * I_ + k;
            else                 src = Ah + (size_t)(row0 + ar) * NH + (k - (HAS_X ? I_ : 0));
            *(float4*)(&sA[ar][ac * 8]) = *(const float4*)src;
        }
        // stage B tile: 128 gate-cols x 64 k
#pragma unroll
        for (int p = 0; p < 4; ++p) {
            int n = p * 32 + ar;                      // 0..127
            int j = (n >> 5) * NH + h0 + (n & 31);    // global gate-col
            *(float4*)(&sB[n][ac * 8]) = *(const float4*)(&W[(size_t)j * KD + k0 + ac * 8]);
        }
        __syncthreads();
#pragma unroll
        for (int ks = 0; ks < 2; ++ks) {
            half8 a0 = *(const half8*)(&sA[n15][ks * 32 + q * 8]);
            half8 a1 = *(const half8*)(&sA[16 + n15][ks * 32 + q * 8]);
            half8 b0 = *(const half8*)(&sB[wave * 32 + n15][ks * 32 + q * 8]);
            half8 b1 = *(const half8*)(&sB[wave * 32 + 16 + n15][ks * 32 + q * 8]);
            acc[0][0] = __builtin_amdgcn_mfma_f32_16x16x32_f16(a0, b0, acc[0][0], 0, 0, 0);
            acc[0][1] = __builtin_amdgcn_mfma_f32_16x16x32_f16(a0, b1, acc[0][1], 0, 0, 0);
            acc[1][0] = __builtin_amdgcn_mfma_f32_16x16x32_f16(a1, b0, acc[1][0], 0, 0, 0);
            acc[1][1] = __builtin_amdgcn_mfma_f32_16x16x32_f16(a1, b1, acc[1][1], 0, 0, 0);
        }
    }

    __syncthreads();   // done reading sA/sB; reuse as pre
    float (*pre)[132] = (float(*)[132])smem;
#pragma unroll
    for (int m = 0; m < 2; ++m)
#pragma unroll
        for (int nt = 0; nt < 2; ++nt)
#pragma unroll
            for (int r = 0; r < 4; ++r)
                pre[m * 16 + q * 4 + r][wave * 32 + nt * 16 + n15] = acc[m][nt][r];
    __syncthreads();

    const int kk = tid & 31;
#pragma unroll
    for (int bb = tid >> 5; bb < 32; bb += 8) {
        int bg = row0 + bb;
        int kg = h0 + kk;
        float pi, pf, pg, po;
        if (BIAS_VEC) {
            pi = pre[bb][kk]      + bias[0 * NH + kg];
            pf = pre[bb][32 + kk] + bias[1 * NH + kg];
            pg = pre[bb][64 + kk] + bias[2 * NH + kg];
            po = pre[bb][96 + kk] + bias[3 * NH + kg];
        } else {
            const float* fx = bias + (size_t)bg * 4 * NH;
            pi = pre[bb][kk]      + fx[0 * NH + kg];
            pf = pre[bb][32 + kk] + fx[1 * NH + kg];
            pg = pre[bb][64 + kk] + fx[2 * NH + kg];
            po = pre[bb][96 + kk] + fx[3 * NH + kg];
        }
        float ig = sigmoidf_(pi);
        float fg = sigmoidf_(pf);
        float gg = tanhf_(pg);
        float og = sigmoidf_(po);
        size_t sidx = (size_t)bg * NH + kg;
        float c = fg * c_state[sidx] + ig * gg;
        c_state[sidx] = c;
        float h = og * tanhf_(c);
        h_out[sidx] = (_Float16)h;
        if (WRITE_OUT) out32[((size_t)bg * T_ + out_t) * NH + kg] = h;
    }
}

// ---------------- launch ----------------

extern "C" void kernel_launch(void* const* d_in, const int* in_sizes, int n_in,
                              void* d_out_v, int out_size, void* d_ws, size_t ws_size,
                              hipStream_t stream) {
    (void)in_sizes; (void)n_in; (void)out_size; (void)ws_size;
    const float* x    = (const float*)d_in[0];
    const float* eWih = (const float*)d_in[1];
    const float* eWhh = (const float*)d_in[2];
    const float* ebih = (const float*)d_in[3];
    const float* ebhh = (const float*)d_in[4];
    const float* efcW = (const float*)d_in[5];
    const float* efcb = (const float*)d_in[6];
    const float* dfcW = (const float*)d_in[7];
    const float* dfcb = (const float*)d_in[8];
    const float* dWih = (const float*)d_in[9];
    const float* dWhh = (const float*)d_in[10];
    const float* dbih = (const float*)d_in[11];
    const float* dbhh = (const float*)d_in[12];
    float* d_out = (float*)d_out_v;

    char* ws = (char*)d_ws;
    size_t off = 0;
    auto carve = [&](size_t bytes) {
        char* p = ws + off;
        off += (bytes + 255) & ~(size_t)255;
        return p;
    };
    _Float16* x16   = (_Float16*)carve((size_t)B_ * T_ * I_ * 2);   // 33.6 MB
    _Float16* Wc16  = (_Float16*)carve((size_t)4 * H_ * 1536 * 2);  // 12.6 MB
    _Float16* Wr16  = (_Float16*)carve((size_t)4 * I_ * I_ * 2);    // 2.1 MB
    float*    biasE = (float*)carve((size_t)4 * H_ * 4);
    float*    fixedb= (float*)carve((size_t)B_ * 4 * I_ * 4);       // 2 MB
    float*    dec1  = (float*)carve((size_t)B_ * H_ * 4);           // 1 MB
    _Float16* h16e0 = (_Float16*)carve((size_t)B_ * H_ * 2);
    _Float16* h16e1 = (_Float16*)carve((size_t)B_ * H_ * 2);
    float*    c_e   = (float*)carve((size_t)B_ * H_ * 4);
    _Float16* h16d0 = (_Float16*)carve((size_t)B_ * I_ * 2);
    _Float16* h16d1 = (_Float16*)carve((size_t)B_ * I_ * 2);
    float*    c_d   = (float*)carve((size_t)B_ * I_ * 4);

    hipMemsetAsync(h16e0, 0, (size_t)B_ * H_ * 2, stream);
    hipMemsetAsync(c_e,   0, (size_t)B_ * H_ * 4, stream);
    hipMemsetAsync(h16d0, 0, (size_t)B_ * I_ * 2, stream);
    hipMemsetAsync(c_d,   0, (size_t)B_ * I_ * 4, stream);

    cast_x_kernel<<<dim3((B_ * T_ * I_ / 8 + 255) / 256), 256, 0, stream>>>(x, x16, B_ * T_ * I_ / 8);
    prep_encW_kernel<<<dim3(1536 / 256, 4 * H_), 256, 0, stream>>>(eWih, eWhh, Wc16);
    prep_bias_kernel<<<dim3((4 * H_ + 255) / 256), 256, 0, stream>>>(ebih, ebhh, biasE);
    prep_decW_kernel<<<dim3(I_ / 256, 4 * I_), 256, 0, stream>>>(dWih, dWhh, Wr16);

    _Float16* he[2] = {h16e0, h16e1};
    for (int s = 0; s < T_; ++s) {
        lstm_step_kernel<H_, 1536, true, true, false>
            <<<dim3(H_ / 32, B_ / 32), 256, 0, stream>>>(
                x16, s, he[s & 1], Wc16, biasE, c_e, he[(s + 1) & 1], nullptr, 0);
    }

    float* embd = d_out + (size_t)B_ * T_ * I_;
    // embd = relu(c_final @ encfc_W.T + encfc_b)   [256 x 256], K=1024
    small_gemm_kernel<<<dim3(E_ / 32, B_ / 32), 256, 0, stream>>>(
        c_e, H_, efcW, H_, efcb, nullptr, embd, E_, H_, 1);
    // dec_first = relu(embd @ decfc_W.T + decfc_b) [256 x 1024], K=256
    small_gemm_kernel<<<dim3(H_ / 32, B_ / 32), 256, 0, stream>>>(
        embd, E_, dfcW, E_, dfcb, nullptr, dec1, H_, E_, 1);
    // fixed = dec_first @ dec_Wih[:, :H].T + (dec_bih + dec_bhh) [256 x 2048], K=1024
    small_gemm_kernel<<<dim3(4 * I_ / 32, B_ / 32), 256, 0, stream>>>(
        dec1, H_, dWih, H_ + I_, dbih, dbhh, fixedb, 4 * I_, H_, 0);

    _Float16* hd[2] = {h16d0, h16d1};
    for (int s = 0; s < T_; ++s) {
        lstm_step_kernel<I_, 512, false, false, true>
            <<<dim3(I_ / 32, B_ / 32), 256, 0, stream>>>(
                nullptr, 0, hd[s & 1], Wr16, fixedb, c_d, hd[(s + 1) & 1], d_out, T_ - 1 - s);
    }
}